// Round 5
// baseline (322.276 us; speedup 1.0000x reference)
//
#include <hip/hip_runtime.h>
#include <hip/hip_bf16.h>

// Problem constants
#define T_TOK 2048
#define HID   1024
#define FF    3584
#define NE    8
#define TOPK  2
#define GRIDY 24          // >= max tiles at BM=256: 16 + 7

typedef __bf16 bf16x8 __attribute__((ext_vector_type(8)));
typedef float  f32x4  __attribute__((ext_vector_type(4)));

// ---- workspace layout (bytes) ----
#define WS_COUNTS   0u
#define WS_OFFSETS  64u
#define WS_TILECNT  128u
#define WS_TLE      256u
#define WS_TLM      512u
#define WS_TOPKI    4096u
#define WS_TOPKW    20480u
#define WS_SLOTPOS  36864u
#define WS_SLOTROW  53248u
#define WS_ROUTETOK 69632u
#define WS_XG       131072u                           // ushort[4096*1024] (8 MB), swizzled
#define WS_ACT      (WS_XG + 4096u*1024u*2u)          // ushort[4096*3584] (29.4 MB), swizzled
#define WS_Y        (WS_ACT + 4096u*3584u*2u)         // float[ks*4096*1024]
#define Y_STRIDE    (4096u*1024u)

static __device__ __forceinline__ unsigned short f2bf(float f) {
    unsigned int u = __builtin_bit_cast(unsigned int, f);
    u += 0x7FFFu + ((u >> 16) & 1u);
    return (unsigned short)(u >> 16);
}
static __device__ __forceinline__ unsigned int pack2(float a, float b) {
    unsigned int ua = __builtin_bit_cast(unsigned int, a) + 0x8000u;
    unsigned int ub = __builtin_bit_cast(unsigned int, b) + 0x8000u;
    return (ua >> 16) | (ub & 0xFFFF0000u);
}
static __device__ __forceinline__ void gl_lds16(const void* g, void* l) {
    __builtin_amdgcn_global_load_lds((const __attribute__((address_space(1))) unsigned int*)g,
                                     (__attribute__((address_space(3))) unsigned int*)l, 16, 0, 0);
}

// ---------------- router ----------------
__global__ __launch_bounds__(256) void k_router(
    const float* __restrict__ x, const float* __restrict__ gw,
    int* __restrict__ counts, int* __restrict__ topki,
    float* __restrict__ topkw, int* __restrict__ slotpos)
{
    int t = blockIdx.x * 4 + (threadIdx.x >> 6);
    int l = threadIdx.x & 63;
    const float* xr = x + (size_t)t * HID;
    float acc[NE];
#pragma unroll
    for (int e = 0; e < NE; ++e) acc[e] = 0.f;
#pragma unroll
    for (int i = 0; i < 4; ++i) {
        int h = l * 4 + i * 256;
        float4 xv = *(const float4*)(xr + h);
#pragma unroll
        for (int e = 0; e < NE; ++e) {
            float4 g = *(const float4*)(gw + e * HID + h);
            acc[e] += xv.x * g.x + xv.y * g.y + xv.z * g.z + xv.w * g.w;
        }
    }
#pragma unroll
    for (int e = 0; e < NE; ++e) {
#pragma unroll
        for (int off = 32; off; off >>= 1) acc[e] += __shfl_xor(acc[e], off);
    }
    if (l == 0) {
        float best = -1e30f, second = -1e30f;
        int bi = 0, si = 0;
#pragma unroll
        for (int e = 0; e < NE; ++e) {
            float v = acc[e];
            if (v > best) { second = best; si = bi; best = v; bi = e; }
            else if (v > second) { second = v; si = e; }
        }
        float w0 = 1.f / (1.f + __expf(second - best));
        float w1 = 1.f - w0;
        topki[2 * t] = bi;  topki[2 * t + 1] = si;
        topkw[2 * t] = w0;  topkw[2 * t + 1] = w1;
        slotpos[2 * t]     = atomicAdd(&counts[bi], 1);
        slotpos[2 * t + 1] = atomicAdd(&counts[si], 1);
    }
}

// ---------------- prefix + tile list (BM=256) ----------------
__global__ void k_prefix(const int* __restrict__ counts, int* __restrict__ offsets,
                         int* __restrict__ tle, int* __restrict__ tlm,
                         int* __restrict__ tilecnt) {
    if (threadIdx.x == 0) {
        int o = 0;
#pragma unroll
        for (int e = 0; e < NE; ++e) { offsets[e] = o; o += counts[e]; }
        int n = 0;
        for (int e = 0; e < NE; ++e) {
            int t = (counts[e] + 255) >> 8;
            for (int i = 0; i < t; ++i) { tle[n] = e; tlm[n] = i; ++n; }
        }
        tilecnt[0] = n;
    }
}

// ---------------- fill routing ----------------
__global__ void k_fill(const int* __restrict__ topki, const int* __restrict__ slotpos,
                       const int* __restrict__ offsets, int* __restrict__ routetok,
                       int* __restrict__ slotrow) {
    int j = blockIdx.x * blockDim.x + threadIdx.x;
    if (j >= T_TOK * TOPK) return;
    int e = topki[j];
    int row = offsets[e] + slotpos[j];
    routetok[row] = j >> 1;
    slotrow[j] = row;
}

// ---------------- gather + convert + swizzle ----------------
__global__ void k_gather(const float* __restrict__ x, const int* __restrict__ routetok,
                         unsigned short* __restrict__ xg) {
    int j = blockIdx.x * blockDim.x + threadIdx.x;
    int r = j >> 8;
    int c = (j & 255) * 4;
    int tok = routetok[r];
    float4 v = *(const float4*)(x + (size_t)tok * HID + c);
    ushort4 o;
    o.x = f2bf(v.x); o.y = f2bf(v.y); o.z = f2bf(v.z); o.w = f2bf(v.w);
    int sc = c ^ ((r & 7) << 3);          // granule swizzle keyed on global row
    *(ushort4*)(xg + (size_t)r * HID + sc) = o;
}

// ---------------- GEMM1: act = silu(Xg@w1^T) * (Xg@w3^T) ----------------
// block 256 thr (4 waves 2x2), tile 256 rows x 64 F, BK=64, per-wave 128x32x2mat
__global__ __launch_bounds__(256, 2) void k_gemm1(
    const unsigned short* __restrict__ xg, const float* __restrict__ w1,
    const float* __restrict__ w3, const int* __restrict__ counts,
    const int* __restrict__ offsets, const int* __restrict__ tle,
    const int* __restrict__ tlm, const int* __restrict__ tilecnt,
    unsigned short* __restrict__ act)
{
    int by = blockIdx.y;
    if (by >= tilecnt[0]) return;
    int e = tle[by];
    int rbase = tlm[by] * 256;
    int cnt = counts[e], obase = offsets[e];
    int fbase = blockIdx.x * 64;

    __shared__ __align__(16) unsigned short lA[2][256 * 64];
    __shared__ __align__(16) unsigned short lB1[64 * 64];
    __shared__ __align__(16) unsigned short lB3[64 * 64];

    int tid = threadIdx.x;
    int lane = tid & 63, wv = tid >> 6;
    int wr = wv >> 1, wc = wv & 1;

    // A DMA sources: 8 rounds, thread -> row tid>>3 (+32j), granule tid&7
    const unsigned short* asrc[8];
#pragma unroll
    for (int j = 0; j < 8; ++j) {
        int r = rbase + (tid >> 3) + 32 * j;
        int rg = obase + (r < cnt ? r : (cnt - 1));
        asrc[j] = xg + (size_t)rg * HID + (tid & 7) * 8;
    }
    unsigned short* adst = &lA[0][0] + tid * 8;   // round j adds 32*j*64 elems

    // B staging: thread -> row rb = tid&63, k-quarter = wv*16
    int rb = tid & 63;
    int swzW = (rb & 7) << 3;
    const float* pb1 = w1 + ((size_t)e * FF + fbase + rb) * HID + wv * 16;
    const float* pb3 = w3 + ((size_t)e * FF + fbase + rb) * HID + wv * 16;
    unsigned short* wb1a = lB1 + rb * 64 + ((wv * 16) ^ swzW);
    unsigned short* wb1b = lB1 + rb * 64 + ((wv * 16 + 8) ^ swzW);
    unsigned short* wb3a = lB3 + rb * 64 + ((wv * 16) ^ swzW);
    unsigned short* wb3b = lB3 + rb * 64 + ((wv * 16 + 8) ^ swzW);

    int swzA = (((obase & 7) + (lane & 7)) & 7) << 3;
    int swzB = (lane & 7) << 3;
    int klane = (lane >> 4) * 8;

    f32x4 accg[8][2], accu[8][2];
#pragma unroll
    for (int m = 0; m < 8; ++m)
#pragma unroll
        for (int n = 0; n < 2; ++n) {
            accg[m][n] = (f32x4){0.f, 0.f, 0.f, 0.f};
            accu[m][n] = (f32x4){0.f, 0.f, 0.f, 0.f};
        }

    // prologue: DMA(0), B-load(0)
#pragma unroll
    for (int j = 0; j < 8; ++j) gl_lds16(asrc[j], adst + 32 * j * 64);
    float4 r1[4], r3[4];
#pragma unroll
    for (int j = 0; j < 4; ++j) {
        r1[j] = *(const float4*)(pb1 + 4 * j);
        r3[j] = *(const float4*)(pb3 + 4 * j);
    }

    for (int kt = 0; kt < HID / 64; ++kt) {
        int cur = kt & 1;
        if (kt < HID / 64 - 1) {
            unsigned short* nd = &lA[cur ^ 1][0] + tid * 8;
#pragma unroll
            for (int j = 0; j < 8; ++j) gl_lds16(asrc[j] + (kt + 1) * 64, nd + 32 * j * 64);
        }
        // write B (compiler inserts counted vmcnt wait for r1/r3 -> also drains DMA(kt))
        {
            uint4 q;
            q.x = pack2(r1[0].x, r1[0].y); q.y = pack2(r1[0].z, r1[0].w);
            q.z = pack2(r1[1].x, r1[1].y); q.w = pack2(r1[1].z, r1[1].w);
            *(uint4*)wb1a = q;
            q.x = pack2(r1[2].x, r1[2].y); q.y = pack2(r1[2].z, r1[2].w);
            q.z = pack2(r1[3].x, r1[3].y); q.w = pack2(r1[3].z, r1[3].w);
            *(uint4*)wb1b = q;
            q.x = pack2(r3[0].x, r3[0].y); q.y = pack2(r3[0].z, r3[0].w);
            q.z = pack2(r3[1].x, r3[1].y); q.w = pack2(r3[1].z, r3[1].w);
            *(uint4*)wb3a = q;
            q.x = pack2(r3[2].x, r3[2].y); q.y = pack2(r3[2].z, r3[2].w);
            q.z = pack2(r3[3].x, r3[3].y); q.w = pack2(r3[3].z, r3[3].w);
            *(uint4*)wb3b = q;
        }
        if (kt < HID / 64 - 1) {
            int kof = (kt + 1) * 64;
#pragma unroll
            for (int j = 0; j < 4; ++j) {
                r1[j] = *(const float4*)(pb1 + kof + 4 * j);
                r3[j] = *(const float4*)(pb3 + kof + 4 * j);
            }
        }
        asm volatile("s_waitcnt lgkmcnt(0)" ::: "memory");
        __builtin_amdgcn_s_barrier();
        __builtin_amdgcn_sched_barrier(0);
        const unsigned short* A = &lA[cur][0];
#pragma unroll
        for (int kk = 0; kk < 2; ++kk) {
            int kc = kk * 32 + klane;
            int kA = kc ^ swzA, kB = kc ^ swzB;
            bf16x8 b1f[2], b3f[2];
#pragma unroll
            for (int n = 0; n < 2; ++n) {
                b1f[n] = *(const bf16x8*)(lB1 + (wc * 32 + n * 16 + (lane & 15)) * 64 + kB);
                b3f[n] = *(const bf16x8*)(lB3 + (wc * 32 + n * 16 + (lane & 15)) * 64 + kB);
            }
#pragma unroll
            for (int m = 0; m < 8; ++m) {
                bf16x8 a = *(const bf16x8*)(A + (wr * 128 + m * 16 + (lane & 15)) * 64 + kA);
#pragma unroll
                for (int n = 0; n < 2; ++n) {
                    accg[m][n] = __builtin_amdgcn_mfma_f32_16x16x32_bf16(a, b1f[n], accg[m][n], 0, 0, 0);
                    accu[m][n] = __builtin_amdgcn_mfma_f32_16x16x32_bf16(a, b3f[n], accu[m][n], 0, 0, 0);
                }
            }
        }
        __builtin_amdgcn_sched_barrier(0);
        asm volatile("s_waitcnt lgkmcnt(0)" ::: "memory");
        __builtin_amdgcn_s_barrier();
    }

    // epilogue: silu(g)*u -> act (swizzled cols)
#pragma unroll
    for (int m = 0; m < 8; ++m)
#pragma unroll
        for (int n = 0; n < 2; ++n)
#pragma unroll
            for (int r = 0; r < 4; ++r) {
                int lr = wr * 128 + m * 16 + (lane >> 4) * 4 + r;
                if (rbase + lr < cnt) {
                    float g = accg[m][n][r], u = accu[m][n][r];
                    float s = g / (1.f + __expf(-g));
                    int row = obase + rbase + lr;
                    int col = fbase + wc * 32 + n * 16 + (lane & 15);
                    int scol = col ^ ((row & 7) << 3);
                    act[(size_t)row * FF + scol] = f2bf(s * u);
                }
            }
}

// ---------------- GEMM2: y[z] = act @ w2^T ----------------
// block 256 thr (4 waves 2x2), tile 256 rows x 128 H, BK=64, split-K=ks
__global__ __launch_bounds__(256, 2) void k_gemm2(
    const unsigned short* __restrict__ act, const float* __restrict__ w2,
    const int* __restrict__ counts, const int* __restrict__ offsets,
    const int* __restrict__ tle, const int* __restrict__ tlm,
    const int* __restrict__ tilecnt, float* __restrict__ y, int ks)
{
    int by = blockIdx.y;
    if (by >= tilecnt[0]) return;
    int e = tle[by];
    int rbase = tlm[by] * 256;
    int cnt = counts[e], obase = offsets[e];
    int hbase = blockIdx.x * 128;
    int z = blockIdx.z;
    const int KTOT = FF / 64;                  // 56
    int per = (KTOT + ks - 1) / ks;
    int kt0 = z * per;
    int ktn = min(KTOT, kt0 + per) - kt0;

    __shared__ __align__(16) unsigned short lA[2][256 * 64];
    __shared__ __align__(16) unsigned short lB[128 * 64];

    int tid = threadIdx.x;
    int lane = tid & 63, wv = tid >> 6;
    int wr = wv >> 1, wc = wv & 1;

    const unsigned short* asrc[8];
#pragma unroll
    for (int j = 0; j < 8; ++j) {
        int r = rbase + (tid >> 3) + 32 * j;
        int rg = obase + (r < cnt ? r : (cnt - 1));
        asrc[j] = act + (size_t)rg * FF + kt0 * 64 + (tid & 7) * 8;
    }
    unsigned short* adst = &lA[0][0] + tid * 8;

    // B staging: thread -> H-row hr = tid&127, k-half kh = tid>>7
    int hr = tid & 127, kh = tid >> 7;
    int swzW = (hr & 7) << 3;
    const float* pb = w2 + ((size_t)e * HID + hbase + hr) * FF + kt0 * 64 + kh * 32;
    unsigned short* wb[4];
#pragma unroll
    for (int j = 0; j < 4; ++j)
        wb[j] = lB + hr * 64 + ((kh * 32 + j * 8) ^ swzW);

    int swzA = (((obase & 7) + (lane & 7)) & 7) << 3;
    int swzB = (lane & 7) << 3;
    int klane = (lane >> 4) * 8;

    f32x4 acc[8][4];
#pragma unroll
    for (int m = 0; m < 8; ++m)
#pragma unroll
        for (int n = 0; n < 4; ++n) acc[m][n] = (f32x4){0.f, 0.f, 0.f, 0.f};

#pragma unroll
    for (int j = 0; j < 8; ++j) gl_lds16(asrc[j], adst + 32 * j * 64);
    float4 rw[8];
#pragma unroll
    for (int j = 0; j < 8; ++j) rw[j] = *(const float4*)(pb + 4 * j);

    for (int kt = 0; kt < ktn; ++kt) {
        int cur = kt & 1;
        if (kt < ktn - 1) {
            unsigned short* nd = &lA[cur ^ 1][0] + tid * 8;
#pragma unroll
            for (int j = 0; j < 8; ++j) gl_lds16(asrc[j] + (kt + 1) * 64, nd + 32 * j * 64);
        }
        {
            uint4 q;
#pragma unroll
            for (int j = 0; j < 4; ++j) {
                q.x = pack2(rw[2 * j].x, rw[2 * j].y);
                q.y = pack2(rw[2 * j].z, rw[2 * j].w);
                q.z = pack2(rw[2 * j + 1].x, rw[2 * j + 1].y);
                q.w = pack2(rw[2 * j + 1].z, rw[2 * j + 1].w);
                *(uint4*)wb[j] = q;
            }
        }
        if (kt < ktn - 1) {
            int kof = (kt + 1) * 64;
#pragma unroll
            for (int j = 0; j < 8; ++j) rw[j] = *(const float4*)(pb + kof + 4 * j);
        }
        asm volatile("s_waitcnt lgkmcnt(0)" ::: "memory");
        __builtin_amdgcn_s_barrier();
        __builtin_amdgcn_sched_barrier(0);
        const unsigned short* A = &lA[cur][0];
#pragma unroll
        for (int kk = 0; kk < 2; ++kk) {
            int kc = kk * 32 + klane;
            int kA = kc ^ swzA, kB = kc ^ swzB;
            bf16x8 bf[4];
#pragma unroll
            for (int n = 0; n < 4; ++n)
                bf[n] = *(const bf16x8*)(lB + (wc * 64 + n * 16 + (lane & 15)) * 64 + kB);
#pragma unroll
            for (int m = 0; m < 8; ++m) {
                bf16x8 a = *(const bf16x8*)(A + (wr * 128 + m * 16 + (lane & 15)) * 64 + kA);
#pragma unroll
                for (int n = 0; n < 4; ++n)
                    acc[m][n] = __builtin_amdgcn_mfma_f32_16x16x32_bf16(a, bf[n], acc[m][n], 0, 0, 0);
            }
        }
        __builtin_amdgcn_sched_barrier(0);
        asm volatile("s_waitcnt lgkmcnt(0)" ::: "memory");
        __builtin_amdgcn_s_barrier();
    }

    float* yz = y + (size_t)z * Y_STRIDE;
#pragma unroll
    for (int m = 0; m < 8; ++m)
#pragma unroll
        for (int n = 0; n < 4; ++n)
#pragma unroll
            for (int r = 0; r < 4; ++r) {
                int lr = wr * 128 + m * 16 + (lane >> 4) * 4 + r;
                if (rbase + lr < cnt) {
                    int col = hbase + wc * 64 + n * 16 + (lane & 15);
                    yz[(size_t)(obase + rbase + lr) * HID + col] = acc[m][n][r];
                }
            }
}

// ---------------- combine ----------------
__global__ void k_combine(const float* __restrict__ y, const int* __restrict__ slotrow,
                          const float* __restrict__ topkw, float* __restrict__ out, int ks) {
    int j = blockIdx.x * blockDim.x + threadIdx.x;
    int t = j >> 8, c = j & 255;
    int r0 = slotrow[2 * t], r1 = slotrow[2 * t + 1];
    float w0 = topkw[2 * t], w1 = topkw[2 * t + 1];
    float4 a = {0.f, 0.f, 0.f, 0.f}, b = {0.f, 0.f, 0.f, 0.f};
    for (int z = 0; z < ks; ++z) {
        const float4* yz = (const float4*)(y + (size_t)z * Y_STRIDE);
        float4 av = yz[(size_t)r0 * 256 + c];
        float4 bv = yz[(size_t)r1 * 256 + c];
        a.x += av.x; a.y += av.y; a.z += av.z; a.w += av.w;
        b.x += bv.x; b.y += bv.y; b.z += bv.z; b.w += bv.w;
    }
    float4 o;
    o.x = w0 * a.x + w1 * b.x;
    o.y = w0 * a.y + w1 * b.y;
    o.z = w0 * a.z + w1 * b.z;
    o.w = w0 * a.w + w1 * b.w;
    ((float4*)out)[j] = o;
}

extern "C" void kernel_launch(void* const* d_in, const int* in_sizes, int n_in,
                              void* d_out, int out_size, void* d_ws, size_t ws_size,
                              hipStream_t stream) {
    const float* x  = (const float*)d_in[0];
    const float* gw = (const float*)d_in[1];
    const float* w1 = (const float*)d_in[2];
    const float* w3 = (const float*)d_in[3];
    const float* w2 = (const float*)d_in[4];
    float* out = (float*)d_out;

    char* ws = (char*)d_ws;
    int*   counts   = (int*)(ws + WS_COUNTS);
    int*   offsets  = (int*)(ws + WS_OFFSETS);
    int*   tilecnt  = (int*)(ws + WS_TILECNT);
    int*   tle      = (int*)(ws + WS_TLE);
    int*   tlm      = (int*)(ws + WS_TLM);
    int*   topki    = (int*)(ws + WS_TOPKI);
    float* topkw    = (float*)(ws + WS_TOPKW);
    int*   slotpos  = (int*)(ws + WS_SLOTPOS);
    int*   slotrow  = (int*)(ws + WS_SLOTROW);
    int*   routetok = (int*)(ws + WS_ROUTETOK);
    unsigned short* xg   = (unsigned short*)(ws + WS_XG);
    unsigned short* actb = (unsigned short*)(ws + WS_ACT);
    float* yb = (float*)(ws + WS_Y);

    // split-K for gemm2 sized to workspace
    size_t ybytes = (size_t)Y_STRIDE * 4;
    int ks = 1;
    if (ws_size >= (size_t)WS_Y + 3 * ybytes) ks = 3;
    else if (ws_size >= (size_t)WS_Y + 2 * ybytes) ks = 2;

    hipMemsetAsync(counts, 0, 64, stream);
    k_router<<<T_TOK / 4, 256, 0, stream>>>(x, gw, counts, topki, topkw, slotpos);
    k_prefix<<<1, 64, 0, stream>>>(counts, offsets, tle, tlm, tilecnt);
    k_fill<<<16, 256, 0, stream>>>(topki, slotpos, offsets, routetok, slotrow);
    k_gather<<<4096, 256, 0, stream>>>(x, routetok, xg);
    k_gemm1<<<dim3(FF / 64, GRIDY, 1), 256, 0, stream>>>(xg, w1, w3, counts, offsets, tle, tlm, tilecnt, actb);
    k_gemm2<<<dim3(HID / 128, GRIDY, ks), 256, 0, stream>>>(actb, w2, counts, offsets, tle, tlm, tilecnt, yb, ks);
    k_combine<<<2048, 256, 0, stream>>>(yb, slotrow, topkw, out, ks);
}